// Round 2
// baseline (1523.784 us; speedup 1.0000x reference)
//
#include <hip/hip_runtime.h>
#include <stdint.h>
#include <math.h>

#define NOISE_LEVEL 0.02f
#define CROSSTALK   0.05f
#define COHERENCE   0.03f

// RNG scheme for jax.random.normal bits:
//  3: threefry_partitionable=True (modern JAX default), bit_width=32:
//     bits[i] = o0 ^ o1 of threefry(key, hi32(i)=0, lo32(i)=i)   <-- XOR fold
//  0: o1 only (WRONG - round 1 showed absmax 0.13 = noise-realization mismatch)
//  1: o0 only
//  2: legacy non-partitionable split-iota scheme for 2^24-element arrays
#define RNG_VARIANT 3

#define TF_ROUND(x0,x1,R) { x0 += x1; x1 = ((x1 << (R)) | (x1 >> (32-(R)))); x1 ^= x0; }

__host__ __device__ inline void threefry2x32(uint32_t k0, uint32_t k1,
                                             uint32_t x0, uint32_t x1,
                                             uint32_t& o0, uint32_t& o1)
{
  uint32_t ks2 = k0 ^ k1 ^ 0x1BD11BDAu;
  x0 += k0; x1 += k1;
  TF_ROUND(x0,x1,13) TF_ROUND(x0,x1,15) TF_ROUND(x0,x1,26) TF_ROUND(x0,x1,6)
  x0 += k1; x1 += ks2 + 1u;
  TF_ROUND(x0,x1,17) TF_ROUND(x0,x1,29) TF_ROUND(x0,x1,16) TF_ROUND(x0,x1,24)
  x0 += ks2; x1 += k0 + 2u;
  TF_ROUND(x0,x1,13) TF_ROUND(x0,x1,15) TF_ROUND(x0,x1,26) TF_ROUND(x0,x1,6)
  x0 += k0; x1 += k1 + 3u;
  TF_ROUND(x0,x1,17) TF_ROUND(x0,x1,29) TF_ROUND(x0,x1,16) TF_ROUND(x0,x1,24)
  x0 += k1; x1 += ks2 + 4u;
  TF_ROUND(x0,x1,13) TF_ROUND(x0,x1,15) TF_ROUND(x0,x1,26) TF_ROUND(x0,x1,6)
  o0 = x0 + ks2; o1 = x1 + k0 + 5u;
}

__device__ inline uint32_t jax_bits(uint32_t k0, uint32_t k1, uint32_t idx)
{
#if RNG_VARIANT == 3
  uint32_t o0, o1; threefry2x32(k0, k1, 0u, idx, o0, o1); return o0 ^ o1;
#elif RNG_VARIANT == 0
  uint32_t o0, o1; threefry2x32(k0, k1, 0u, idx, o0, o1); (void)o0; return o1;
#elif RNG_VARIANT == 1
  uint32_t o0, o1; threefry2x32(k0, k1, 0u, idx, o0, o1); (void)o1; return o0;
#else
  uint32_t o0, o1;
  const uint32_t HALF = 1u << 23;   // arrays here are exactly 2^24 elements
  if (idx < HALF) { threefry2x32(k0, k1, idx, idx + HALF, o0, o1); return o0; }
  else            { threefry2x32(k0, k1, idx - HALF, idx, o0, o1); return o1; }
#endif
}

// JAX random.normal(float32): u ~ uniform[nextafter(-1,0), 1);  n = sqrt(2)*erfinv(u)
// uniform: f = bitcast(bits>>9 | 0x3f800000) - 1;  u = f*(hi-lo) + lo; (hi-lo)==2.0f exactly
__device__ inline float jax_normal(uint32_t k0, uint32_t k1, uint32_t idx)
{
  uint32_t bits = jax_bits(k0, k1, idx);
  float f = __uint_as_float((bits >> 9) | 0x3f800000u) - 1.0f;   // [0,1)
  float u = fmaf(f, 2.0f, -0.99999994f);
  u = fmaxf(-0.99999994f, u);
  // XLA ErfInv f32 (Giles approximation)
  float w = -__logf(fmaf(-u, u, 1.0f));
  float p;
  if (w < 5.0f) {
    w -= 2.5f;
    p = 2.81022636e-08f;
    p = fmaf(p, w, 3.43273939e-07f);
    p = fmaf(p, w, -3.5233877e-06f);
    p = fmaf(p, w, -4.39150654e-06f);
    p = fmaf(p, w, 0.00021858087f);
    p = fmaf(p, w, -0.00125372503f);
    p = fmaf(p, w, -0.00417768164f);
    p = fmaf(p, w, 0.246640727f);
    p = fmaf(p, w, 1.50140941f);
  } else {
    w = sqrtf(w) - 3.0f;
    p = -0.000200214257f;
    p = fmaf(p, w, 0.000100950558f);
    p = fmaf(p, w, 0.00134934322f);
    p = fmaf(p, w, -0.00367342844f);
    p = fmaf(p, w, 0.00573950773f);
    p = fmaf(p, w, -0.0076224613f);
    p = fmaf(p, w, 0.00943887047f);
    p = fmaf(p, w, 1.00167406f);
    p = fmaf(p, w, 2.83297682f);
  }
  return 1.41421354f * (p * u);
}

// |p| <= ~0.17, so a short even polynomial beats reference accuracy easily
__device__ inline float cos_small(float p)
{
  float p2 = p * p;
  return 1.0f + p2 * (-0.5f + p2 * (4.16666679e-02f + p2 * (-1.38888892e-03f)));
}

// ---------------------------------------------------------------------------
// Fused GEMM: out = tanh(A @ W^T + bias) + 0.02*normal(key, flat_idx)
// Also accumulates per-column sum of |out| into colabs (for thermal crosstalk).
// A: [M,K] row-major (optionally tanh applied on load), W: [N,K] row-major.
// ---------------------------------------------------------------------------
#define BM 128
#define BN 128
#define BK 32
#define LDA (BM + 4)

template<int TANH_A>
__global__ __launch_bounds__(256)
void gemm_fused(const float* __restrict__ A, const float* __restrict__ W,
                const float* __restrict__ bias, float* __restrict__ out,
                float* __restrict__ colabs,
                int M, int N, int K, uint32_t nk0, uint32_t nk1)
{
  __shared__ float As[BK][LDA];
  __shared__ float Bs[BK][LDA];

  const int t = threadIdx.x;
  const int nbm = M / BM;
  const int bm = blockIdx.x % nbm;
  const int bn = blockIdx.x / nbm;
  const int blockM = bm * BM;
  const int blockN = bn * BN;

  const int tm = t >> 4;     // 0..15
  const int tn = t & 15;     // 0..15
  const int m0 = tm * 8;

  const int rbase = t >> 3;  // 0..31
  const int kq = t & 7;      // 0..7

  float acc[8][8];
  #pragma unroll
  for (int i = 0; i < 8; ++i)
    #pragma unroll
    for (int j = 0; j < 8; ++j) acc[i][j] = 0.0f;

  const float* Aptr = A + (size_t)(blockM + rbase) * K + kq * 4;
  const float* Wptr = W + (size_t)(blockN + rbase) * K + kq * 4;

  for (int kt = 0; kt < K; kt += BK) {
    float4 av[4], bv[4];
    #pragma unroll
    for (int c = 0; c < 4; ++c) {
      av[c] = *(const float4*)(Aptr + (size_t)(32 * c) * K + kt);
      bv[c] = *(const float4*)(Wptr + (size_t)(32 * c) * K + kt);
    }
    if (TANH_A) {
      #pragma unroll
      for (int c = 0; c < 4; ++c) {
        av[c].x = tanhf(av[c].x); av[c].y = tanhf(av[c].y);
        av[c].z = tanhf(av[c].z); av[c].w = tanhf(av[c].w);
      }
    }
    __syncthreads();
    #pragma unroll
    for (int c = 0; c < 4; ++c) {
      int r = rbase + 32 * c;
      As[kq*4+0][r] = av[c].x; As[kq*4+1][r] = av[c].y;
      As[kq*4+2][r] = av[c].z; As[kq*4+3][r] = av[c].w;
      Bs[kq*4+0][r] = bv[c].x; Bs[kq*4+1][r] = bv[c].y;
      Bs[kq*4+2][r] = bv[c].z; Bs[kq*4+3][r] = bv[c].w;
    }
    __syncthreads();
    #pragma unroll 8
    for (int kk = 0; kk < BK; ++kk) {
      float4 a0 = *(const float4*)&As[kk][m0];
      float4 a1 = *(const float4*)&As[kk][m0 + 4];
      float4 b0 = *(const float4*)&Bs[kk][tn * 4];
      float4 b1 = *(const float4*)&Bs[kk][64 + tn * 4];
      float ar[8] = {a0.x, a0.y, a0.z, a0.w, a1.x, a1.y, a1.z, a1.w};
      float br[8] = {b0.x, b0.y, b0.z, b0.w, b1.x, b1.y, b1.z, b1.w};
      #pragma unroll
      for (int i = 0; i < 8; ++i)
        #pragma unroll
        for (int j = 0; j < 8; ++j)
          acc[i][j] = fmaf(ar[i], br[j], acc[i][j]);
    }
  }

  // --- epilogue: bias + tanh + JAX noise + store + column |v| partials ---
  float bcols[8];
  #pragma unroll
  for (int j = 0; j < 8; ++j) {
    int c = (j < 4) ? tn*4 + j : 64 + tn*4 + (j - 4);
    bcols[j] = bias[blockN + c];
  }
  float cpart[8];
  #pragma unroll
  for (int j = 0; j < 8; ++j) cpart[j] = 0.0f;

  #pragma unroll
  for (int i = 0; i < 8; ++i) {
    int gr = blockM + m0 + i;
    float vs[8];
    #pragma unroll
    for (int j = 0; j < 8; ++j) {
      int c = (j < 4) ? tn*4 + j : 64 + tn*4 + (j - 4);
      int gc = blockN + c;
      float nrm = jax_normal(nk0, nk1, (uint32_t)(gr * N + gc));
      float v = tanhf(acc[i][j] + bcols[j]) + NOISE_LEVEL * nrm;
      vs[j] = v;
      cpart[j] += fabsf(v);
    }
    float* orow = out + (size_t)gr * N + blockN;
    *(float4*)(orow + tn * 4)      = make_float4(vs[0], vs[1], vs[2], vs[3]);
    *(float4*)(orow + 64 + tn * 4) = make_float4(vs[4], vs[5], vs[6], vs[7]);
  }

  __syncthreads();
  float* cp = &As[0][0];          // reuse LDS: [16][128] partials
  #pragma unroll
  for (int j = 0; j < 8; ++j) {
    int c = (j < 4) ? tn*4 + j : 64 + tn*4 + (j - 4);
    cp[tm * 128 + c] = cpart[j];
  }
  __syncthreads();
  if (t < 128) {
    float s = 0.0f;
    #pragma unroll
    for (int r = 0; r < 16; ++r) s += cp[r * 128 + t];
    atomicAdd(&colabs[blockN + t], s);
  }
}

// ---------------------------------------------------------------------------
// thermal = 0.7*prev + 0.3*(colabs*CROSSTALK);  tn[i] = CROSSTALK * sum_j thermal[j]/(i-j)^2
// ---------------------------------------------------------------------------
__global__ __launch_bounds__(256)
void thermal_tn(const float* __restrict__ colabs, const float* __restrict__ prev_thermal,
                float* __restrict__ thermal_out, float* __restrict__ tn_out, int has_prev)
{
  __shared__ float th[2048];
  __shared__ float inv[2048];
  const int t = threadIdx.x;
  for (int j = t; j < 2048; j += 256) {
    float lt = colabs[j] * CROSSTALK;
    float pv = has_prev ? prev_thermal[j] : 0.0f;
    th[j] = 0.7f * pv + 0.3f * lt;
    float d = (float)j;
    inv[j] = (j == 0) ? 0.0f : 1.0f / (d * d);
  }
  __syncthreads();
  const int i = blockIdx.x * 256 + t;
  float s = 0.0f;
  #pragma unroll 4
  for (int j = 0; j < 2048; ++j) {
    int d = i - j; d = d < 0 ? -d : d;
    s += th[j] * inv[d];
  }
  tn_out[i] = s * CROSSTALK;
  thermal_out[i] = th[i];
}

// ---------------------------------------------------------------------------
// x[b,h] = (x[b,h] + tn[h]); then coherence: x += (x*cos(0.03*normal)-x)*0.03
// ---------------------------------------------------------------------------
__global__ __launch_bounds__(256)
void coherence_pass(float* __restrict__ x, const float* __restrict__ tn,
                    uint32_t pk0, uint32_t pk1, int total4)
{
  int g = blockIdx.x * blockDim.x + threadIdx.x;
  const int stride = gridDim.x * blockDim.x;
  for (; g < total4; g += stride) {
    size_t base = (size_t)g * 4;
    float4 v = *(float4*)&x[base];
    int col = (int)(base & 2047);
    const float4 tv = *(const float4*)&tn[col];
    float vv[4] = {v.x + tv.x, v.y + tv.y, v.z + tv.z, v.w + tv.w};
    #pragma unroll
    for (int e = 0; e < 4; ++e) {
      float ph = COHERENCE * jax_normal(pk0, pk1, (uint32_t)base + e);
      float cp = cos_small(ph);
      vv[e] = vv[e] + (vv[e] * cp - vv[e]) * COHERENCE;
    }
    *(float4*)&x[base] = make_float4(vv[0], vv[1], vv[2], vv[3]);
  }
}

// ---------------------------------------------------------------------------
// Final: x2 = (a2 + tn2)*coherence;  out[b,:] = x2[b,:] @ Wout^T + bout  (D_out=2)
// One wave per row, shuffle reduction.
// ---------------------------------------------------------------------------
__global__ __launch_bounds__(256)
void final_out(const float* __restrict__ a2, const float* __restrict__ tn2,
               const float* __restrict__ Wout, const float* __restrict__ bout,
               float* __restrict__ out, uint32_t pk0, uint32_t pk1)
{
  const int wave = threadIdx.x >> 6;
  const int lane = threadIdx.x & 63;
  const int b = blockIdx.x * 4 + wave;
  const float* row = a2 + (size_t)b * 2048;
  float acc0 = 0.0f, acc1 = 0.0f;
  #pragma unroll
  for (int i = 0; i < 8; ++i) {
    int h = lane * 4 + i * 256;
    float4 v  = *(const float4*)&row[h];
    float4 tv = *(const float4*)&tn2[h];
    float4 w0 = *(const float4*)&Wout[h];
    float4 w1 = *(const float4*)&Wout[2048 + h];
    float xs[4]  = {v.x + tv.x, v.y + tv.y, v.z + tv.z, v.w + tv.w};
    float w0s[4] = {w0.x, w0.y, w0.z, w0.w};
    float w1s[4] = {w1.x, w1.y, w1.z, w1.w};
    uint32_t fb = (uint32_t)(b * 2048 + h);
    #pragma unroll
    for (int e = 0; e < 4; ++e) {
      float ph = COHERENCE * jax_normal(pk0, pk1, fb + e);
      float cp = cos_small(ph);
      float xv = xs[e] + (xs[e] * cp - xs[e]) * COHERENCE;
      acc0 = fmaf(xv, w0s[e], acc0);
      acc1 = fmaf(xv, w1s[e], acc1);
    }
  }
  #pragma unroll
  for (int off = 32; off > 0; off >>= 1) {
    acc0 += __shfl_down(acc0, off);
    acc1 += __shfl_down(acc1, off);
  }
  if (lane == 0) {
    out[(size_t)b * 2 + 0] = acc0 + bout[0];
    out[(size_t)b * 2 + 1] = acc1 + bout[1];
  }
}

extern "C" void kernel_launch(void* const* d_in, const int* in_sizes, int n_in,
                              void* d_out, int out_size, void* d_ws, size_t ws_size,
                              hipStream_t stream)
{
  (void)in_sizes; (void)n_in; (void)out_size; (void)ws_size;
  const float* x    = (const float*)d_in[0];
  const float* W1   = (const float*)d_in[1];
  const float* b1   = (const float*)d_in[2];
  const float* W2   = (const float*)d_in[3];
  const float* b2   = (const float*)d_in[4];
  const float* Wout = (const float*)d_in[5];
  const float* bout = (const float*)d_in[6];
  float* out = (float*)d_out;

  const int M = 8192, H = 2048, Din = 1024;

  char* ws = (char*)d_ws;
  float* a1 = (float*)ws;                                        // 64 MB
  float* a2 = (float*)(ws + (size_t)M * H * sizeof(float));      // 64 MB
  float* small = (float*)(ws + 2 * (size_t)M * H * sizeof(float));
  float* colabs1  = small + 0 * H;
  float* colabs2  = small + 1 * H;
  float* thermal1 = small + 2 * H;
  float* thermal2 = small + 3 * H;
  float* tn1      = small + 4 * H;
  float* tn2      = small + 5 * H;

  // Derive the four fold_in keys on host: key(42) = (0,42); fold_in(key, d) =
  // threefry_2x32(key, [0, d]) -> (o0, o1)
  uint32_t kn0a, kn0b, kp0a, kp0b, kn1a, kn1b, kp1a, kp1b;
  threefry2x32(0u, 42u, 0u, 0u, kn0a, kn0b);   // noise, layer 0
  threefry2x32(0u, 42u, 0u, 1u, kp0a, kp0b);   // phase, layer 0
  threefry2x32(0u, 42u, 0u, 2u, kn1a, kn1b);   // noise, layer 1
  threefry2x32(0u, 42u, 0u, 3u, kp1a, kp1b);   // phase, layer 1

  hipMemsetAsync(colabs1, 0, 2 * H * sizeof(float), stream);     // colabs1+colabs2

  const int nblk = (M / BM) * (H / BN);   // 64*16 = 1024
  gemm_fused<1><<<nblk, 256, 0, stream>>>(x, W1, b1, a1, colabs1, M, H, Din, kn0a, kn0b);
  thermal_tn<<<H / 256, 256, 0, stream>>>(colabs1, nullptr, thermal1, tn1, 0);
  coherence_pass<<<2048, 256, 0, stream>>>(a1, tn1, kp0a, kp0b, M * H / 4);
  gemm_fused<0><<<nblk, 256, 0, stream>>>(a1, W2, b2, a2, colabs2, M, H, H, kn1a, kn1b);
  thermal_tn<<<H / 256, 256, 0, stream>>>(colabs2, thermal1, thermal2, tn2, 1);
  final_out<<<M / 4, 256, 0, stream>>>(a2, tn2, Wout, bout, out, kp1a, kp1b);
}

// Round 3
// 672.308 us; speedup vs baseline: 2.2665x; 2.2665x over previous
//
#include <hip/hip_runtime.h>
#include <stdint.h>
#include <math.h>

#define NOISE_LEVEL 0.02f
#define CROSSTALK   0.05f
#define COHERENCE   0.03f

typedef __attribute__((ext_vector_type(8))) short short8;
typedef __attribute__((ext_vector_type(4))) float f32x4;

#define TF_ROUND(x0,x1,R) { x0 += x1; x1 = ((x1 << (R)) | (x1 >> (32-(R)))); x1 ^= x0; }

__host__ __device__ inline void threefry2x32(uint32_t k0, uint32_t k1,
                                             uint32_t x0, uint32_t x1,
                                             uint32_t& o0, uint32_t& o1)
{
  uint32_t ks2 = k0 ^ k1 ^ 0x1BD11BDAu;
  x0 += k0; x1 += k1;
  TF_ROUND(x0,x1,13) TF_ROUND(x0,x1,15) TF_ROUND(x0,x1,26) TF_ROUND(x0,x1,6)
  x0 += k1; x1 += ks2 + 1u;
  TF_ROUND(x0,x1,17) TF_ROUND(x0,x1,29) TF_ROUND(x0,x1,16) TF_ROUND(x0,x1,24)
  x0 += ks2; x1 += k0 + 2u;
  TF_ROUND(x0,x1,13) TF_ROUND(x0,x1,15) TF_ROUND(x0,x1,26) TF_ROUND(x0,x1,6)
  x0 += k0; x1 += k1 + 3u;
  TF_ROUND(x0,x1,17) TF_ROUND(x0,x1,29) TF_ROUND(x0,x1,16) TF_ROUND(x0,x1,24)
  x0 += k1; x1 += ks2 + 4u;
  TF_ROUND(x0,x1,13) TF_ROUND(x0,x1,15) TF_ROUND(x0,x1,26) TF_ROUND(x0,x1,6)
  o0 = x0 + ks2; o1 = x1 + k0 + 5u;
}

// threefry_partitionable bits for 32-bit draws: XOR of the two output words.
__device__ inline uint32_t jax_bits(uint32_t k0, uint32_t k1, uint32_t idx)
{
  uint32_t o0, o1; threefry2x32(k0, k1, 0u, idx, o0, o1); return o0 ^ o1;
}

// JAX random.normal(float32): u ~ uniform[-0.99999994, 1); n = sqrt(2)*erfinv(u)
__device__ inline float jax_normal(uint32_t k0, uint32_t k1, uint32_t idx)
{
  uint32_t bits = jax_bits(k0, k1, idx);
  float f = __uint_as_float((bits >> 9) | 0x3f800000u) - 1.0f;   // [0,1)
  float u = fmaf(f, 2.0f, -0.99999994f);
  u = fmaxf(-0.99999994f, u);
  float w = -__logf(fmaf(-u, u, 1.0f));
  float p;
  if (w < 5.0f) {
    w -= 2.5f;
    p = 2.81022636e-08f;
    p = fmaf(p, w, 3.43273939e-07f);
    p = fmaf(p, w, -3.5233877e-06f);
    p = fmaf(p, w, -4.39150654e-06f);
    p = fmaf(p, w, 0.00021858087f);
    p = fmaf(p, w, -0.00125372503f);
    p = fmaf(p, w, -0.00417768164f);
    p = fmaf(p, w, 0.246640727f);
    p = fmaf(p, w, 1.50140941f);
  } else {
    w = sqrtf(w) - 3.0f;
    p = -0.000200214257f;
    p = fmaf(p, w, 0.000100950558f);
    p = fmaf(p, w, 0.00134934322f);
    p = fmaf(p, w, -0.00367342844f);
    p = fmaf(p, w, 0.00573950773f);
    p = fmaf(p, w, -0.0076224613f);
    p = fmaf(p, w, 0.00943887047f);
    p = fmaf(p, w, 1.00167406f);
    p = fmaf(p, w, 2.83297682f);
  }
  return 1.41421354f * (p * u);
}

__device__ inline float cos_small(float p)
{
  float p2 = p * p;
  return 1.0f + p2 * (-0.5f + p2 * (4.16666679e-02f + p2 * (-1.38888892e-03f)));
}

// round-to-nearest-even fp32 -> bf16, and back
__device__ inline unsigned short bf16_rn(float x)
{
  uint32_t u = __float_as_uint(x);
  uint32_t r = u + 0x7FFFu + ((u >> 16) & 1u);
  return (unsigned short)(r >> 16);
}
__device__ inline float bf16_f(unsigned short h)
{
  return __uint_as_float(((uint32_t)h) << 16);
}

// ---------------------------------------------------------------------------
// tanh pre-pass: xt = tanh(x)   (written into spare workspace; avoids
// re-applying tanh on every A-tile restage in GEMM1)
// ---------------------------------------------------------------------------
__global__ __launch_bounds__(256)
void tanh_pre(const float* __restrict__ x, float* __restrict__ xt, int n4)
{
  int g = blockIdx.x * 256 + threadIdx.x;
  const int stride = gridDim.x * 256;
  for (; g < n4; g += stride) {
    float4 v = *(const float4*)&x[(size_t)g * 4];
    v.x = tanhf(v.x); v.y = tanhf(v.y); v.z = tanhf(v.z); v.w = tanhf(v.w);
    *(float4*)&xt[(size_t)g * 4] = v;
  }
}

// ---------------------------------------------------------------------------
// Split-bf16 MFMA GEMM: out = tanh(A @ W^T + bias) + 0.02*normal(key, r*N+c)
// A [M,K], W [N,K] fp32 row-major. fp32 emulated as Ah*Bh + Ah*Bl + Al*Bh.
// 128x128 tile, BKF=64, 4 waves, 16x16x32 bf16 MFMA, 4x4 frags per wave.
// LDS planes [128][64] bf16 with XOR swizzle idx = r*64 + (c ^ ((r&7)<<3)).
// Also accumulates per-column sum|v| into colabs (atomics).
// ---------------------------------------------------------------------------
#define BM 128
#define BN 128
#define BKF 64

__global__ __launch_bounds__(256)
void gemm_mfma(const float* __restrict__ A, const float* __restrict__ W,
               const float* __restrict__ bias, float* __restrict__ out,
               float* __restrict__ colabs, int M, int N, int K,
               uint32_t nk0, uint32_t nk1)
{
  __shared__ __align__(16) unsigned short Ah[BM * BKF];
  __shared__ __align__(16) unsigned short Al[BM * BKF];
  __shared__ __align__(16) unsigned short Bh[BM * BKF];
  __shared__ __align__(16) unsigned short Bl[BM * BKF];

  const int t = threadIdx.x;
  const int nbm = M / BM;
  const int bm = blockIdx.x % nbm;
  const int bn = blockIdx.x / nbm;
  const int blockM = bm * BM, blockN = bn * BN;

  // staging role: 16 float4-columns x 16 row-groups
  const int col4 = t & 15;
  const int row0 = t >> 4;        // 0..15
  const int c0 = col4 * 4;        // fp32 k-offset within tile

  // compute role
  const int lane = t & 63;
  const int w = t >> 6;
  const int wr = w >> 1, wc = w & 1;
  const int lm = lane & 15, lg = lane >> 4;

  f32x4 acc[4][4];
  #pragma unroll
  for (int i = 0; i < 4; ++i)
    #pragma unroll
    for (int j = 0; j < 4; ++j) acc[i][j] = 0.0f;

  const int nk = K / BKF;
  const float* Abase = A + (size_t)blockM * K + c0;
  const float* Wbase = W + (size_t)blockN * K + c0;

  float4 pa[8], pb[8];
  #pragma unroll
  for (int i = 0; i < 8; ++i) {
    int r = row0 + i * 16;
    pa[i] = *(const float4*)(Abase + (size_t)r * K);
    pb[i] = *(const float4*)(Wbase + (size_t)r * K);
  }

  for (int kt = 0; kt < nk; ++kt) {
    __syncthreads();   // previous compute done -> safe to overwrite LDS
    #pragma unroll
    for (int i = 0; i < 8; ++i) {
      int r = row0 + i * 16;
      int idx = r * BKF + (c0 ^ ((r & 7) << 3));
      float xs[4] = {pa[i].x, pa[i].y, pa[i].z, pa[i].w};
      float ys[4] = {pb[i].x, pb[i].y, pb[i].z, pb[i].w};
      unsigned short ah[4], al[4], bh[4], bl[4];
      #pragma unroll
      for (int e = 0; e < 4; ++e) {
        ah[e] = bf16_rn(xs[e]); al[e] = bf16_rn(xs[e] - bf16_f(ah[e]));
        bh[e] = bf16_rn(ys[e]); bl[e] = bf16_rn(ys[e] - bf16_f(bh[e]));
      }
      *(ushort4*)&Ah[idx] = make_ushort4(ah[0], ah[1], ah[2], ah[3]);
      *(ushort4*)&Al[idx] = make_ushort4(al[0], al[1], al[2], al[3]);
      *(ushort4*)&Bh[idx] = make_ushort4(bh[0], bh[1], bh[2], bh[3]);
      *(ushort4*)&Bl[idx] = make_ushort4(bl[0], bl[1], bl[2], bl[3]);
    }
    __syncthreads();   // staging visible

    if (kt + 1 < nk) {   // prefetch next tile; latency hides under MFMA
      const float* An = Abase + (size_t)(kt + 1) * BKF;
      const float* Wn = Wbase + (size_t)(kt + 1) * BKF;
      #pragma unroll
      for (int i = 0; i < 8; ++i) {
        int r = row0 + i * 16;
        pa[i] = *(const float4*)(An + (size_t)r * K);
        pb[i] = *(const float4*)(Wn + (size_t)r * K);
      }
    }

    #pragma unroll
    for (int ks = 0; ks < 2; ++ks) {
      short8 fa_h[4], fa_l[4], fb_h[4], fb_l[4];
      const int kc = ks * 32 + lg * 8;
      #pragma unroll
      for (int fm = 0; fm < 4; ++fm) {
        int r = wr * 64 + fm * 16 + lm;
        int idx = r * BKF + (kc ^ ((r & 7) << 3));
        fa_h[fm] = *(const short8*)&Ah[idx];
        fa_l[fm] = *(const short8*)&Al[idx];
      }
      #pragma unroll
      for (int fn = 0; fn < 4; ++fn) {
        int r = wc * 64 + fn * 16 + lm;
        int idx = r * BKF + (kc ^ ((r & 7) << 3));
        fb_h[fn] = *(const short8*)&Bh[idx];
        fb_l[fn] = *(const short8*)&Bl[idx];
      }
      #pragma unroll
      for (int fm = 0; fm < 4; ++fm)
        #pragma unroll
        for (int fn = 0; fn < 4; ++fn) {
          acc[fm][fn] = __builtin_amdgcn_mfma_f32_16x16x32_bf16(fa_h[fm], fb_h[fn], acc[fm][fn], 0, 0, 0);
          acc[fm][fn] = __builtin_amdgcn_mfma_f32_16x16x32_bf16(fa_h[fm], fb_l[fn], acc[fm][fn], 0, 0, 0);
          acc[fm][fn] = __builtin_amdgcn_mfma_f32_16x16x32_bf16(fa_l[fm], fb_h[fn], acc[fm][fn], 0, 0, 0);
        }
    }
  }

  // epilogue: C layout col=lane&15, row=(lane>>4)*4+reg  [m89-verified]
  #pragma unroll
  for (int fn = 0; fn < 4; ++fn) {
    int gc = blockN + wc * 64 + fn * 16 + lm;
    float bv = bias[gc];
    float cp = 0.0f;
    #pragma unroll
    for (int fm = 0; fm < 4; ++fm) {
      int gr0 = blockM + wr * 64 + fm * 16 + lg * 4;
      #pragma unroll
      for (int j = 0; j < 4; ++j) {
        int gr = gr0 + j;
        float nrm = jax_normal(nk0, nk1, (uint32_t)(gr * N + gc));
        float v = tanhf(acc[fm][fn][j] + bv) + NOISE_LEVEL * nrm;
        out[(size_t)gr * N + gc] = v;
        cp += fabsf(v);
      }
    }
    cp += __shfl_xor(cp, 16);
    cp += __shfl_xor(cp, 32);
    if (lg == 0) atomicAdd(&colabs[gc], cp);
  }
}

// ---------------------------------------------------------------------------
// thermal = 0.7*prev + 0.3*(colabs*CROSSTALK); tn[i] = CROSSTALK * sum thermal[j]/(i-j)^2
// ---------------------------------------------------------------------------
__global__ __launch_bounds__(256)
void thermal_tn(const float* __restrict__ colabs, const float* __restrict__ prev_thermal,
                float* __restrict__ thermal_out, float* __restrict__ tn_out, int has_prev)
{
  __shared__ float th[2048];
  __shared__ float inv[2048];
  const int t = threadIdx.x;
  for (int j = t; j < 2048; j += 256) {
    float lt = colabs[j] * CROSSTALK;
    float pv = has_prev ? prev_thermal[j] : 0.0f;
    th[j] = 0.7f * pv + 0.3f * lt;
    float d = (float)j;
    inv[j] = (j == 0) ? 0.0f : 1.0f / (d * d);
  }
  __syncthreads();
  const int i = blockIdx.x * 256 + t;
  float s = 0.0f;
  #pragma unroll 4
  for (int j = 0; j < 2048; ++j) {
    int d = i - j; d = d < 0 ? -d : d;
    s += th[j] * inv[d];
  }
  tn_out[i] = s * CROSSTALK;
  thermal_out[i] = th[i];
}

// ---------------------------------------------------------------------------
// x[b,h] = (x[b,h] + tn[h]); then coherence: x += (x*cos(0.03*normal)-x)*0.03
// ---------------------------------------------------------------------------
__global__ __launch_bounds__(256)
void coherence_pass(float* __restrict__ x, const float* __restrict__ tn,
                    uint32_t pk0, uint32_t pk1, int total4)
{
  int g = blockIdx.x * blockDim.x + threadIdx.x;
  const int stride = gridDim.x * blockDim.x;
  for (; g < total4; g += stride) {
    size_t base = (size_t)g * 4;
    float4 v = *(float4*)&x[base];
    int col = (int)(base & 2047);
    const float4 tv = *(const float4*)&tn[col];
    float vv[4] = {v.x + tv.x, v.y + tv.y, v.z + tv.z, v.w + tv.w};
    #pragma unroll
    for (int e = 0; e < 4; ++e) {
      float ph = COHERENCE * jax_normal(pk0, pk1, (uint32_t)base + e);
      float cp = cos_small(ph);
      vv[e] = vv[e] + (vv[e] * cp - vv[e]) * COHERENCE;
    }
    *(float4*)&x[base] = make_float4(vv[0], vv[1], vv[2], vv[3]);
  }
}

// ---------------------------------------------------------------------------
// Final: x2 = (a2 + tn2) with coherence; out[b,:] = x2[b,:] @ Wout^T + bout
// ---------------------------------------------------------------------------
__global__ __launch_bounds__(256)
void final_out(const float* __restrict__ a2, const float* __restrict__ tn2,
               const float* __restrict__ Wout, const float* __restrict__ bout,
               float* __restrict__ out, uint32_t pk0, uint32_t pk1)
{
  const int wave = threadIdx.x >> 6;
  const int lane = threadIdx.x & 63;
  const int b = blockIdx.x * 4 + wave;
  const float* row = a2 + (size_t)b * 2048;
  float acc0 = 0.0f, acc1 = 0.0f;
  #pragma unroll
  for (int i = 0; i < 8; ++i) {
    int h = lane * 4 + i * 256;
    float4 v  = *(const float4*)&row[h];
    float4 tv = *(const float4*)&tn2[h];
    float4 w0 = *(const float4*)&Wout[h];
    float4 w1 = *(const float4*)&Wout[2048 + h];
    float xs[4]  = {v.x + tv.x, v.y + tv.y, v.z + tv.z, v.w + tv.w};
    float w0s[4] = {w0.x, w0.y, w0.z, w0.w};
    float w1s[4] = {w1.x, w1.y, w1.z, w1.w};
    uint32_t fb = (uint32_t)(b * 2048 + h);
    #pragma unroll
    for (int e = 0; e < 4; ++e) {
      float ph = COHERENCE * jax_normal(pk0, pk1, fb + e);
      float cp = cos_small(ph);
      float xv = xs[e] + (xs[e] * cp - xs[e]) * COHERENCE;
      acc0 = fmaf(xv, w0s[e], acc0);
      acc1 = fmaf(xv, w1s[e], acc1);
    }
  }
  #pragma unroll
  for (int off = 32; off > 0; off >>= 1) {
    acc0 += __shfl_down(acc0, off);
    acc1 += __shfl_down(acc1, off);
  }
  if (lane == 0) {
    out[(size_t)b * 2 + 0] = acc0 + bout[0];
    out[(size_t)b * 2 + 1] = acc1 + bout[1];
  }
}

extern "C" void kernel_launch(void* const* d_in, const int* in_sizes, int n_in,
                              void* d_out, int out_size, void* d_ws, size_t ws_size,
                              hipStream_t stream)
{
  (void)in_sizes; (void)n_in; (void)out_size; (void)ws_size;
  const float* x    = (const float*)d_in[0];
  const float* W1   = (const float*)d_in[1];
  const float* b1   = (const float*)d_in[2];
  const float* W2   = (const float*)d_in[3];
  const float* b2   = (const float*)d_in[4];
  const float* Wout = (const float*)d_in[5];
  const float* bout = (const float*)d_in[6];
  float* out = (float*)d_out;

  const int M = 8192, H = 2048, Din = 1024;

  char* ws = (char*)d_ws;
  float* a1 = (float*)ws;                                        // 64 MB
  float* a2 = (float*)(ws + (size_t)M * H * sizeof(float));      // 64 MB (also holds tanh(x) pre-GEMM2)
  float* small = (float*)(ws + 2 * (size_t)M * H * sizeof(float));
  float* colabs1  = small + 0 * H;
  float* colabs2  = small + 1 * H;
  float* thermal1 = small + 2 * H;
  float* thermal2 = small + 3 * H;
  float* tn1      = small + 4 * H;
  float* tn2      = small + 5 * H;

  // fold_in keys: key(42) = (0,42); fold_in(key, d) = threefry(key, [0,d])
  uint32_t kn0a, kn0b, kp0a, kp0b, kn1a, kn1b, kp1a, kp1b;
  threefry2x32(0u, 42u, 0u, 0u, kn0a, kn0b);   // noise, layer 0
  threefry2x32(0u, 42u, 0u, 1u, kp0a, kp0b);   // phase, layer 0
  threefry2x32(0u, 42u, 0u, 2u, kn1a, kn1b);   // noise, layer 1
  threefry2x32(0u, 42u, 0u, 3u, kp1a, kp1b);   // phase, layer 1

  hipMemsetAsync(colabs1, 0, 2 * H * sizeof(float), stream);     // colabs1+colabs2

  const int nblk = (M / BM) * (H / BN);   // 64*16 = 1024

  // tanh(x) into a2's region (a2 is not needed until GEMM2 writes it)
  tanh_pre<<<2048, 256, 0, stream>>>(x, a2, M * Din / 4);
  gemm_mfma<<<nblk, 256, 0, stream>>>(a2, W1, b1, a1, colabs1, M, H, Din, kn0a, kn0b);
  thermal_tn<<<H / 256, 256, 0, stream>>>(colabs1, nullptr, thermal1, tn1, 0);
  coherence_pass<<<2048, 256, 0, stream>>>(a1, tn1, kp0a, kp0b, M * H / 4);
  gemm_mfma<<<nblk, 256, 0, stream>>>(a1, W2, b2, a2, colabs2, M, H, H, kn1a, kn1b);
  thermal_tn<<<H / 256, 256, 0, stream>>>(colabs2, thermal1, thermal2, tn2, 1);
  final_out<<<M / 4, 256, 0, stream>>>(a2, tn2, Wout, bout, out, kp1a, kp1b);
}

// Round 4
// 628.491 us; speedup vs baseline: 2.4245x; 1.0697x over previous
//
#include <hip/hip_runtime.h>
#include <stdint.h>
#include <math.h>

#define NOISE_LEVEL 0.02f
#define CROSSTALK   0.05f
#define COHERENCE   0.03f

typedef __attribute__((ext_vector_type(8))) short short8;
typedef __attribute__((ext_vector_type(4))) float f32x4;

#define TF_ROUND(x0,x1,R) { x0 += x1; x1 = ((x1 << (R)) | (x1 >> (32-(R)))); x1 ^= x0; }

__host__ __device__ inline void threefry2x32(uint32_t k0, uint32_t k1,
                                             uint32_t x0, uint32_t x1,
                                             uint32_t& o0, uint32_t& o1)
{
  uint32_t ks2 = k0 ^ k1 ^ 0x1BD11BDAu;
  x0 += k0; x1 += k1;
  TF_ROUND(x0,x1,13) TF_ROUND(x0,x1,15) TF_ROUND(x0,x1,26) TF_ROUND(x0,x1,6)
  x0 += k1; x1 += ks2 + 1u;
  TF_ROUND(x0,x1,17) TF_ROUND(x0,x1,29) TF_ROUND(x0,x1,16) TF_ROUND(x0,x1,24)
  x0 += ks2; x1 += k0 + 2u;
  TF_ROUND(x0,x1,13) TF_ROUND(x0,x1,15) TF_ROUND(x0,x1,26) TF_ROUND(x0,x1,6)
  x0 += k0; x1 += k1 + 3u;
  TF_ROUND(x0,x1,17) TF_ROUND(x0,x1,29) TF_ROUND(x0,x1,16) TF_ROUND(x0,x1,24)
  x0 += k1; x1 += ks2 + 4u;
  TF_ROUND(x0,x1,13) TF_ROUND(x0,x1,15) TF_ROUND(x0,x1,26) TF_ROUND(x0,x1,6)
  o0 = x0 + ks2; o1 = x1 + k0 + 5u;
}

// threefry_partitionable bits for 32-bit draws: XOR of the two output words.
__device__ inline uint32_t jax_bits(uint32_t k0, uint32_t k1, uint32_t idx)
{
  uint32_t o0, o1; threefry2x32(k0, k1, 0u, idx, o0, o1); return o0 ^ o1;
}

// JAX random.normal(float32): u ~ uniform[-0.99999994, 1); n = sqrt(2)*erfinv(u)
__device__ inline float jax_normal(uint32_t k0, uint32_t k1, uint32_t idx)
{
  uint32_t bits = jax_bits(k0, k1, idx);
  float f = __uint_as_float((bits >> 9) | 0x3f800000u) - 1.0f;   // [0,1)
  float u = fmaf(f, 2.0f, -0.99999994f);
  u = fmaxf(-0.99999994f, u);
  float w = -__logf(fmaf(-u, u, 1.0f));
  float p;
  if (w < 5.0f) {
    w -= 2.5f;
    p = 2.81022636e-08f;
    p = fmaf(p, w, 3.43273939e-07f);
    p = fmaf(p, w, -3.5233877e-06f);
    p = fmaf(p, w, -4.39150654e-06f);
    p = fmaf(p, w, 0.00021858087f);
    p = fmaf(p, w, -0.00125372503f);
    p = fmaf(p, w, -0.00417768164f);
    p = fmaf(p, w, 0.246640727f);
    p = fmaf(p, w, 1.50140941f);
  } else {
    w = sqrtf(w) - 3.0f;
    p = -0.000200214257f;
    p = fmaf(p, w, 0.000100950558f);
    p = fmaf(p, w, 0.00134934322f);
    p = fmaf(p, w, -0.00367342844f);
    p = fmaf(p, w, 0.00573950773f);
    p = fmaf(p, w, -0.0076224613f);
    p = fmaf(p, w, 0.00943887047f);
    p = fmaf(p, w, 1.00167406f);
    p = fmaf(p, w, 2.83297682f);
  }
  return 1.41421354f * (p * u);
}

__device__ inline float cos_small(float p)
{
  float p2 = p * p;
  return 1.0f + p2 * (-0.5f + p2 * (4.16666679e-02f + p2 * (-1.38888892e-03f)));
}

// round-to-nearest-even fp32 -> bf16, and back
__device__ inline unsigned short bf16_rn(float x)
{
  uint32_t u = __float_as_uint(x);
  uint32_t r = u + 0x7FFFu + ((u >> 16) & 1u);
  return (unsigned short)(r >> 16);
}
__device__ inline float bf16_f(unsigned short h)
{
  return __uint_as_float(((uint32_t)h) << 16);
}

// ---------------------------------------------------------------------------
// split_pass: hi/lo bf16 planes of in (optionally tanh first).
// Numerics identical to the in-GEMM split of round 3.
// ---------------------------------------------------------------------------
__global__ __launch_bounds__(256)
void split_pass(const float* __restrict__ in, unsigned short* __restrict__ hi,
                unsigned short* __restrict__ lo, int n4, int do_tanh)
{
  int g = blockIdx.x * 256 + threadIdx.x;
  const int stride = gridDim.x * 256;
  for (; g < n4; g += stride) {
    float4 v = *(const float4*)&in[(size_t)g * 4];
    if (do_tanh) {
      v.x = tanhf(v.x); v.y = tanhf(v.y); v.z = tanhf(v.z); v.w = tanhf(v.w);
    }
    float xs[4] = {v.x, v.y, v.z, v.w};
    ushort4 h, l;
    unsigned short* hp = &h.x; unsigned short* lp = &l.x;
    #pragma unroll
    for (int e = 0; e < 4; ++e) {
      hp[e] = bf16_rn(xs[e]);
      lp[e] = bf16_rn(xs[e] - bf16_f(hp[e]));
    }
    *(ushort4*)&hi[(size_t)g * 4] = h;
    *(ushort4*)&lo[(size_t)g * 4] = l;
  }
}

// ---------------------------------------------------------------------------
// Pure-bf16 4-plane MFMA GEMM (fp32 via Ah*Bh + Ah*Bl + Al*Bh):
//   out = tanh(A @ W^T + bias) + 0.02*normal(key, r*N+c); colabs += sum|v|.
// A,W given as pre-split bf16 hi/lo planes, row-major [rows][K].
// 128x128 tile, BK=32, 4 waves; wave w stages plane w via global_load_lds
// (width 16, linear LDS dest). Row stride 64B -> fragment ds_read_b128 is
// bank-uniform without swizzle.
// ---------------------------------------------------------------------------
#define BM 128
#define BN 128
#define BK 32

__global__ __launch_bounds__(256)
void gemm_mfma(const unsigned short* __restrict__ Agh, const unsigned short* __restrict__ Agl,
               const unsigned short* __restrict__ Bgh, const unsigned short* __restrict__ Bgl,
               const float* __restrict__ bias, float* __restrict__ out,
               float* __restrict__ colabs, int M, int N, int K,
               uint32_t nk0, uint32_t nk1)
{
  __shared__ __align__(16) unsigned short sAh[BM * BK];
  __shared__ __align__(16) unsigned short sAl[BM * BK];
  __shared__ __align__(16) unsigned short sBh[BM * BK];
  __shared__ __align__(16) unsigned short sBl[BM * BK];

  const int t = threadIdx.x;
  const int nbm = M / BM;
  const int bm = blockIdx.x % nbm;
  const int bn = blockIdx.x / nbm;
  const int blockM = bm * BM, blockN = bn * BN;

  const int lane = t & 63;
  const int w = t >> 6;
  const int wr = w >> 1, wc = w & 1;
  const int lm = lane & 15, lg = lane >> 4;

  // staging: wave w owns one plane; 8 insts x (64 lanes x 16B) = 8KB plane tile
  const unsigned short* gplane;
  unsigned short* lplane;
  int grow0;
  if (w == 0)      { gplane = Agh; lplane = sAh; grow0 = blockM; }
  else if (w == 1) { gplane = Agl; lplane = sAl; grow0 = blockM; }
  else if (w == 2) { gplane = Bgh; lplane = sBh; grow0 = blockN; }
  else             { gplane = Bgl; lplane = sBl; grow0 = blockN; }
  const unsigned short* gsrc =
      gplane + (size_t)(grow0 + (lane >> 2)) * K + (lane & 3) * 8;

  f32x4 acc[4][4];
  #pragma unroll
  for (int i = 0; i < 4; ++i)
    #pragma unroll
    for (int j = 0; j < 4; ++j) acc[i][j] = 0.0f;

  const int nk = K / BK;
  for (int kt = 0; kt < nk; ++kt) {
    __syncthreads();                       // prior compute done; LDS reusable
    const unsigned short* g = gsrc + kt * BK;
    #pragma unroll
    for (int i = 0; i < 8; ++i)
      __builtin_amdgcn_global_load_lds((const void*)(g + (size_t)i * 16 * K),
                                       (void*)(lplane + i * 512), 16, 0, 0);
    __syncthreads();                       // loads drained (vmcnt0 before barrier)

    short8 fah[4], fal[4], fbh[4], fbl[4];
    #pragma unroll
    for (int fm = 0; fm < 4; ++fm) {
      int idx = (wr * 64 + fm * 16 + lm) * BK + lg * 8;
      fah[fm] = *(const short8*)&sAh[idx];
      fal[fm] = *(const short8*)&sAl[idx];
    }
    #pragma unroll
    for (int fn = 0; fn < 4; ++fn) {
      int idx = (wc * 64 + fn * 16 + lm) * BK + lg * 8;
      fbh[fn] = *(const short8*)&sBh[idx];
      fbl[fn] = *(const short8*)&sBl[idx];
    }
    #pragma unroll
    for (int fm = 0; fm < 4; ++fm)
      #pragma unroll
      for (int fn = 0; fn < 4; ++fn) {
        acc[fm][fn] = __builtin_amdgcn_mfma_f32_16x16x32_bf16(fah[fm], fbh[fn], acc[fm][fn], 0, 0, 0);
        acc[fm][fn] = __builtin_amdgcn_mfma_f32_16x16x32_bf16(fah[fm], fbl[fn], acc[fm][fn], 0, 0, 0);
        acc[fm][fn] = __builtin_amdgcn_mfma_f32_16x16x32_bf16(fal[fm], fbh[fn], acc[fm][fn], 0, 0, 0);
      }
  }

  // epilogue: C layout col=lane&15, row=(lane>>4)*4+reg  [m89-verified]
  #pragma unroll
  for (int fn = 0; fn < 4; ++fn) {
    int gc = blockN + wc * 64 + fn * 16 + lm;
    float bv = bias[gc];
    float cp = 0.0f;
    #pragma unroll
    for (int fm = 0; fm < 4; ++fm) {
      int gr0 = blockM + wr * 64 + fm * 16 + lg * 4;
      #pragma unroll
      for (int j = 0; j < 4; ++j) {
        int gr = gr0 + j;
        float nrm = jax_normal(nk0, nk1, (uint32_t)(gr * N + gc));
        float v = tanhf(acc[fm][fn][j] + bv) + NOISE_LEVEL * nrm;
        out[(size_t)gr * N + gc] = v;
        cp += fabsf(v);
      }
    }
    cp += __shfl_xor(cp, 16);
    cp += __shfl_xor(cp, 32);
    if (lg == 0) atomicAdd(&colabs[gc], cp);
  }
}

// ---------------------------------------------------------------------------
// thermal = 0.7*prev + 0.3*(colabs*CROSSTALK); tn[i] = CROSSTALK * sum thermal[j]/(i-j)^2
// ---------------------------------------------------------------------------
__global__ __launch_bounds__(256)
void thermal_tn(const float* __restrict__ colabs, const float* __restrict__ prev_thermal,
                float* __restrict__ thermal_out, float* __restrict__ tn_out, int has_prev)
{
  __shared__ float th[2048];
  __shared__ float inv[2048];
  const int t = threadIdx.x;
  for (int j = t; j < 2048; j += 256) {
    float lt = colabs[j] * CROSSTALK;
    float pv = has_prev ? prev_thermal[j] : 0.0f;
    th[j] = 0.7f * pv + 0.3f * lt;
    float d = (float)j;
    inv[j] = (j == 0) ? 0.0f : 1.0f / (d * d);
  }
  __syncthreads();
  const int i = blockIdx.x * 256 + t;
  float s = 0.0f;
  #pragma unroll 4
  for (int j = 0; j < 2048; ++j) {
    int d = i - j; d = d < 0 ? -d : d;
    s += th[j] * inv[d];
  }
  tn_out[i] = s * CROSSTALK;
  thermal_out[i] = th[i];
}

// ---------------------------------------------------------------------------
// coherence + split: v = (x + tn) with phase interference, written as bf16
// hi/lo planes (GEMM2's A operand). Same RNG and same split arithmetic.
// ---------------------------------------------------------------------------
__global__ __launch_bounds__(256)
void coherence_split(const float* __restrict__ x, const float* __restrict__ tn,
                     unsigned short* __restrict__ hi, unsigned short* __restrict__ lo,
                     uint32_t pk0, uint32_t pk1, int total4)
{
  int g = blockIdx.x * blockDim.x + threadIdx.x;
  const int stride = gridDim.x * blockDim.x;
  for (; g < total4; g += stride) {
    size_t base = (size_t)g * 4;
    float4 v = *(const float4*)&x[base];
    int col = (int)(base & 2047);
    const float4 tv = *(const float4*)&tn[col];
    float vv[4] = {v.x + tv.x, v.y + tv.y, v.z + tv.z, v.w + tv.w};
    ushort4 h, l;
    unsigned short* hp = &h.x; unsigned short* lp = &l.x;
    #pragma unroll
    for (int e = 0; e < 4; ++e) {
      float ph = COHERENCE * jax_normal(pk0, pk1, (uint32_t)base + e);
      float cp = cos_small(ph);
      float xv = vv[e] + (vv[e] * cp - vv[e]) * COHERENCE;
      hp[e] = bf16_rn(xv);
      lp[e] = bf16_rn(xv - bf16_f(hp[e]));
    }
    *(ushort4*)&hi[base] = h;
    *(ushort4*)&lo[base] = l;
  }
}

// ---------------------------------------------------------------------------
// Final: x2 = (a2 + tn2) with coherence; out[b,:] = x2[b,:] @ Wout^T + bout
// ---------------------------------------------------------------------------
__global__ __launch_bounds__(256)
void final_out(const float* __restrict__ a2, const float* __restrict__ tn2,
               const float* __restrict__ Wout, const float* __restrict__ bout,
               float* __restrict__ out, uint32_t pk0, uint32_t pk1)
{
  const int wave = threadIdx.x >> 6;
  const int lane = threadIdx.x & 63;
  const int b = blockIdx.x * 4 + wave;
  const float* row = a2 + (size_t)b * 2048;
  float acc0 = 0.0f, acc1 = 0.0f;
  #pragma unroll
  for (int i = 0; i < 8; ++i) {
    int h = lane * 4 + i * 256;
    float4 v  = *(const float4*)&row[h];
    float4 tv = *(const float4*)&tn2[h];
    float4 w0 = *(const float4*)&Wout[h];
    float4 w1 = *(const float4*)&Wout[2048 + h];
    float xs[4]  = {v.x + tv.x, v.y + tv.y, v.z + tv.z, v.w + tv.w};
    float w0s[4] = {w0.x, w0.y, w0.z, w0.w};
    float w1s[4] = {w1.x, w1.y, w1.z, w1.w};
    uint32_t fb = (uint32_t)(b * 2048 + h);
    #pragma unroll
    for (int e = 0; e < 4; ++e) {
      float ph = COHERENCE * jax_normal(pk0, pk1, fb + e);
      float cp = cos_small(ph);
      float xv = xs[e] + (xs[e] * cp - xs[e]) * COHERENCE;
      acc0 = fmaf(xv, w0s[e], acc0);
      acc1 = fmaf(xv, w1s[e], acc1);
    }
  }
  #pragma unroll
  for (int off = 32; off > 0; off >>= 1) {
    acc0 += __shfl_down(acc0, off);
    acc1 += __shfl_down(acc1, off);
  }
  if (lane == 0) {
    out[(size_t)b * 2 + 0] = acc0 + bout[0];
    out[(size_t)b * 2 + 1] = acc1 + bout[1];
  }
}

extern "C" void kernel_launch(void* const* d_in, const int* in_sizes, int n_in,
                              void* d_out, int out_size, void* d_ws, size_t ws_size,
                              hipStream_t stream)
{
  (void)in_sizes; (void)n_in; (void)out_size; (void)ws_size;
  const float* x    = (const float*)d_in[0];
  const float* W1   = (const float*)d_in[1];
  const float* b1   = (const float*)d_in[2];
  const float* W2   = (const float*)d_in[3];
  const float* b2   = (const float*)d_in[4];
  const float* Wout = (const float*)d_in[5];
  const float* bout = (const float*)d_in[6];
  float* out = (float*)d_out;

  const int M = 8192, H = 2048, Din = 1024;
  const size_t MB64 = (size_t)64 * 1024 * 1024;

  char* ws = (char*)d_ws;
  // P0 [0,64MB): a1 fp32 (GEMM1 out), later reused as a2 fp32 (GEMM2 out)
  float* a_f32 = (float*)ws;
  // P1 [64MB,128MB): first xth/xtl (32MB, GEMM1 A planes, dead after GEMM1),
  //                  then a1h/a1l (64MB, coherence out = GEMM2 A planes)
  unsigned short* p1  = (unsigned short*)(ws + MB64);
  unsigned short* xth = p1;
  unsigned short* xtl = p1 + (size_t)M * Din;
  unsigned short* a1h = p1;
  unsigned short* a1l = p1 + (size_t)M * H;
  // P2 [128MB,152MB): W planes
  unsigned short* wp  = (unsigned short*)(ws + 2 * MB64);
  unsigned short* W1h = wp;
  unsigned short* W1l = wp + (size_t)H * Din;
  unsigned short* W2h = wp + (size_t)2 * H * Din;
  unsigned short* W2l = wp + (size_t)2 * H * Din + (size_t)H * H;
  // small arrays
  float* small = (float*)(ws + 2 * MB64 + (size_t)24 * 1024 * 1024);
  float* colabs1  = small + 0 * H;
  float* colabs2  = small + 1 * H;
  float* thermal1 = small + 2 * H;
  float* thermal2 = small + 3 * H;
  float* tn1      = small + 4 * H;
  float* tn2      = small + 5 * H;

  // fold_in keys: key(42) = (0,42); fold_in(key, d) = threefry(key, [0,d])
  uint32_t kn0a, kn0b, kp0a, kp0b, kn1a, kn1b, kp1a, kp1b;
  threefry2x32(0u, 42u, 0u, 0u, kn0a, kn0b);   // noise, layer 0
  threefry2x32(0u, 42u, 0u, 1u, kp0a, kp0b);   // phase, layer 0
  threefry2x32(0u, 42u, 0u, 2u, kn1a, kn1b);   // noise, layer 1
  threefry2x32(0u, 42u, 0u, 3u, kp1a, kp1b);   // phase, layer 1

  hipMemsetAsync(colabs1, 0, 2 * H * sizeof(float), stream);

  // pre-split passes
  split_pass<<<2048, 256, 0, stream>>>(W1, W1h, W1l, H * Din / 4, 0);
  split_pass<<<2048, 256, 0, stream>>>(W2, W2h, W2l, H * H / 4, 0);
  split_pass<<<2048, 256, 0, stream>>>(x, xth, xtl, M * Din / 4, 1);

  const int nblk = (M / BM) * (H / BN);   // 64*16 = 1024
  gemm_mfma<<<nblk, 256, 0, stream>>>(xth, xtl, W1h, W1l, b1, a_f32, colabs1,
                                      M, H, Din, kn0a, kn0b);
  thermal_tn<<<H / 256, 256, 0, stream>>>(colabs1, nullptr, thermal1, tn1, 0);
  coherence_split<<<2048, 256, 0, stream>>>(a_f32, tn1, a1h, a1l, kp0a, kp0b, M * H / 4);
  gemm_mfma<<<nblk, 256, 0, stream>>>(a1h, a1l, W2h, W2l, b2, a_f32, colabs2,
                                      M, H, H, kn1a, kn1b);
  thermal_tn<<<H / 256, 256, 0, stream>>>(colabs2, thermal1, thermal2, tn2, 1);
  final_out<<<M / 4, 256, 0, stream>>>(a_f32, tn2, Wout, bout, out, kp1a, kp1b);
}